// Round 1
// baseline (7778.645 us; speedup 1.0000x reference)
//
#include <hip/hip_runtime.h>
#include <math.h>

#define BB 2
#define NBLK 16
#define KTOK 16
#define NTOK 64
#define DD 1024
#define HH 16
#define AA 64
#define FF 2816
#define LL 4
#define WINW 4
#define EE 80
#define SS 1280
#define BSROWS (BB*SS)   /* 2560 */
#define EPSF 1e-5f

// ---------------------------------------------------------------------------
// Fused (optional bias add) + RMSNorm over D=1024. One block (256 thr) per row.
// bias row index = row % biasRows (pos_emb / ar_bias broadcast); bias may be null.
// ---------------------------------------------------------------------------
__global__ __launch_bounds__(256) void addnorm_kernel(
    const float* __restrict__ src, const float* __restrict__ bias,
    const float* __restrict__ w, float* __restrict__ dst, int biasRows)
{
    int row = blockIdx.x;
    int t = threadIdx.x;
    const float* sp = src + (size_t)row * DD;
    float4 v = *(const float4*)(sp + t * 4);
    if (bias) {
        const float* bp = bias + (size_t)(row % biasRows) * DD;
        float4 bv = *(const float4*)(bp + t * 4);
        v.x += bv.x; v.y += bv.y; v.z += bv.z; v.w += bv.w;
    }
    float ss = v.x*v.x + v.y*v.y + v.z*v.z + v.w*v.w;
    __shared__ float red[4];
    #pragma unroll
    for (int off = 32; off; off >>= 1) ss += __shfl_xor(ss, off);
    int wid = t >> 6;
    if ((t & 63) == 0) red[wid] = ss;
    __syncthreads();
    float tot = red[0] + red[1] + red[2] + red[3];
    float rs = rsqrtf(tot * (1.0f / DD) + EPSF);
    float4 wv = *(const float4*)(w + t * 4);
    float4 o;
    o.x = v.x * rs * wv.x; o.y = v.y * rs * wv.y;
    o.z = v.z * rs * wv.z; o.w = v.w * rs * wv.w;
    *(float4*)(dst + (size_t)row * DD + t * 4) = o;
}

// ---------------------------------------------------------------------------
// C[M,N] = A[M,K] @ W[N,K]^T  (+ optional residual read-modify-write on C)
// Optional row remap for scattering preproc rows into x:
//   r = (m/remapT)*EE + remapOff + (m%remapT)   when remapT > 0
// Tile 64x64, BK=16, 256 threads, 4x4 per thread. All dims divisible (checked).
// ---------------------------------------------------------------------------
__global__ __launch_bounds__(256) void gemm_nt(
    const float* __restrict__ A, const float* __restrict__ W,
    float* __restrict__ C, int M, int N, int Kd,
    int remapT, int remapOff, int addRes)
{
    __shared__ float As[16][64];
    __shared__ float Bs[16][64];
    int t = threadIdx.x;
    int n0 = blockIdx.x * 64, m0 = blockIdx.y * 64;
    int ty = t >> 4, tx = t & 15;
    int lr = t >> 2, lc = (t & 3) << 2;
    float acc[4][4] = {{0.f}};
    for (int k0 = 0; k0 < Kd; k0 += 16) {
        float4 av = *(const float4*)(A + (size_t)(m0 + lr) * Kd + k0 + lc);
        float4 wv = *(const float4*)(W + (size_t)(n0 + lr) * Kd + k0 + lc);
        __syncthreads();
        As[lc+0][lr] = av.x; As[lc+1][lr] = av.y; As[lc+2][lr] = av.z; As[lc+3][lr] = av.w;
        Bs[lc+0][lr] = wv.x; Bs[lc+1][lr] = wv.y; Bs[lc+2][lr] = wv.z; Bs[lc+3][lr] = wv.w;
        __syncthreads();
        #pragma unroll
        for (int kk = 0; kk < 16; ++kk) {
            float4 a = *(const float4*)(&As[kk][ty << 2]);
            float4 b = *(const float4*)(&Bs[kk][tx << 2]);
            acc[0][0] += a.x*b.x; acc[0][1] += a.x*b.y; acc[0][2] += a.x*b.z; acc[0][3] += a.x*b.w;
            acc[1][0] += a.y*b.x; acc[1][1] += a.y*b.y; acc[1][2] += a.y*b.z; acc[1][3] += a.y*b.w;
            acc[2][0] += a.z*b.x; acc[2][1] += a.z*b.y; acc[2][2] += a.z*b.z; acc[2][3] += a.z*b.w;
            acc[3][0] += a.w*b.x; acc[3][1] += a.w*b.y; acc[3][2] += a.w*b.z; acc[3][3] += a.w*b.w;
        }
    }
    #pragma unroll
    for (int i = 0; i < 4; ++i) {
        int m = m0 + (ty << 2) + i;
        int r = remapT ? ((m / remapT) * EE + remapOff + (m % remapT)) : m;
        float* cp = C + (size_t)r * N + n0 + (tx << 2);
        float4 o;
        o.x = acc[i][0]; o.y = acc[i][1]; o.z = acc[i][2]; o.w = acc[i][3];
        if (addRes) {
            float4 old = *(const float4*)cp;
            o.x += old.x; o.y += old.y; o.z += old.z; o.w += old.w;
        }
        *(float4*)cp = o;
    }
}

// ---------------------------------------------------------------------------
// Per (b,s,h) wave: split qkv, l2norm(q,k), rope(q,k). q,v -> (B,H,S,A);
// k -> transposed (B,H,A,S) for coalesced score dots.
// ---------------------------------------------------------------------------
__global__ __launch_bounds__(64) void qkprep_kernel(
    const float* __restrict__ qkv, float* __restrict__ q,
    float* __restrict__ kt, float* __restrict__ v)
{
    int id = blockIdx.x;
    int h = id % HH;
    int s = (id / HH) % SS;
    int b = id / (HH * SS);
    int lane = threadIdx.x;
    const float* base = qkv + (size_t)(b * SS + s) * (3 * DD) + h * AA;
    float qv = base[lane];
    float kv = base[DD + lane];
    float vv = base[2 * DD + lane];
    float sq = qv * qv, sk = kv * kv;
    #pragma unroll
    for (int off = 32; off; off >>= 1) {
        sq += __shfl_xor(sq, off);
        sk += __shfl_xor(sk, off);
    }
    qv = qv / fmaxf(sqrtf(sq), EPSF);
    kv = kv / fmaxf(sqrtf(sk), EPSF);
    int j = lane & 31;
    bool hi = lane >= 32;
    // inv_freq = 10000^(-j/32)
    float invf = __expf(-9.210340371976184f * (float)j * (1.0f / 32.0f));
    float ang = (float)s * invf;
    float c = cosf(ang), sn = sinf(ang);
    float qp = __shfl_xor(qv, 32);
    float kp = __shfl_xor(kv, 32);
    // out[j]    =  x1*c + x2*s   (lane<32: this=x1, partner=x2)
    // out[32+j] = -x1*s + x2*c   (lane>=32: this=x2, partner=x1)
    float qo = hi ? (qv * c - qp * sn) : (qv * c + qp * sn);
    float ko = hi ? (kv * c - kp * sn) : (kv * c + kp * sn);
    size_t bh = (size_t)(b * HH + h);
    q[(bh * SS + s) * AA + lane] = qo;
    kt[(bh * AA + lane) * SS + s] = ko;
    v[(bh * SS + s) * AA + lane] = vv;
}

// ---------------------------------------------------------------------------
// One wave per (b,h,query). Mask structure confines keys to blocks
// [bq-3, bq] => at most 320 keys. Scores -> masked softmax -> PV.
// Output written directly in (B,S,H*A)=(B,S,D) layout for the Wo GEMM.
// ---------------------------------------------------------------------------
__global__ __launch_bounds__(64) void attn_kernel(
    const float* __restrict__ q, const float* __restrict__ kt,
    const float* __restrict__ v, const int* __restrict__ doc,
    float* __restrict__ o)
{
    __shared__ float sQ[AA];
    __shared__ float sP[4 * EE];
    __shared__ int sDoc[NBLK];
    int id = blockIdx.x;
    int qi = id % SS;
    int h = (id / SS) % HH;
    int b = id / (SS * HH);
    int lane = threadIdx.x;
    if (lane < NBLK) sDoc[lane] = doc[b * NBLK + lane];
    size_t bh = (size_t)(b * HH + h);
    sQ[lane] = q[(bh * SS + qi) * AA + lane];
    __syncthreads();
    int bq = qi / EE, rq = qi - bq * EE;
    bool tokq = rq >= KTOK;
    int docq = sDoc[bq];
    int kstart = (bq >= (WINW - 1) ? bq - (WINW - 1) : 0) * EE;
    int kend = (bq + 1) * EE;
    float mx = -3.0e38f;
    for (int kk = kstart + lane; kk < kend; kk += 64) {
        int bk = kk / EE, rk = kk - bk * EE;
        bool tokk = rk >= KTOK;
        int dock = sDoc[bk];
        int dpk = sDoc[bk > 0 ? bk - 1 : 0];
        bool tt = tokq && tokk && (qi >= kk) && (bq < bk + WINW) && (docq == dock);
        bool lm = ((tokq && docq == dpk) || !tokq) && !tokk && (bq == bk);
        float sc = -3.0e38f;
        if (tt || lm) {
            const float* kp = kt + (bh * AA) * SS + kk;
            float accd = 0.f;
            #pragma unroll
            for (int d = 0; d < AA; ++d) accd += sQ[d] * kp[(size_t)d * SS];
            sc = accd * 0.125f;
        }
        sP[kk - kstart] = sc;
        mx = fmaxf(mx, sc);
    }
    #pragma unroll
    for (int off = 32; off; off >>= 1) mx = fmaxf(mx, __shfl_xor(mx, off));
    float sum = 0.f;
    for (int kk = kstart + lane; kk < kend; kk += 64) {
        float e = __expf(sP[kk - kstart] - mx);
        sP[kk - kstart] = e;
        sum += e;
    }
    #pragma unroll
    for (int off = 32; off; off >>= 1) sum += __shfl_xor(sum, off);
    __syncthreads();
    float invs = 1.0f / sum;
    float accv = 0.f;
    const float* vp = v + (bh * SS) * AA + lane;
    for (int kk = kstart; kk < kend; ++kk)
        accv += sP[kk - kstart] * vp[(size_t)kk * AA];
    o[((size_t)b * SS + qi) * DD + h * AA + lane] = accv * invs;
}

// ---------------------------------------------------------------------------
// g = silu(u1) * u2,  u = [u1 | u2] with row length 2F.
// ---------------------------------------------------------------------------
__global__ __launch_bounds__(256) void gate_kernel(
    const float* __restrict__ u, float* __restrict__ g)
{
    int idx = blockIdx.x * 256 + threadIdx.x;   // float4 index
    int m = idx / (FF / 4);
    int f4 = idx % (FF / 4);
    const float* up = u + (size_t)m * (2 * FF) + f4 * 4;
    float4 a = *(const float4*)up;
    float4 b = *(const float4*)(up + FF);
    float4 r;
    r.x = a.x / (1.f + __expf(-a.x)) * b.x;
    r.y = a.y / (1.f + __expf(-a.y)) * b.y;
    r.z = a.z / (1.f + __expf(-a.z)) * b.z;
    r.w = a.w / (1.f + __expf(-a.w)) * b.w;
    *(float4*)(g + (size_t)m * FF + f4 * 4) = r;
}

// ---------------------------------------------------------------------------
// y[b,blk,n,:] = x[b, blk*E + K + n, :]
// ---------------------------------------------------------------------------
__global__ __launch_bounds__(256) void copyout_kernel(
    const float* __restrict__ x, float* __restrict__ y)
{
    int row = blockIdx.x;      // 0 .. 2047
    int t = threadIdx.x;
    int b = row / (NBLK * NTOK);
    int rem = row % (NBLK * NTOK);
    int blk = rem / NTOK;
    int n = rem % NTOK;
    const float* sp = x + ((size_t)b * SS + blk * EE + KTOK + n) * DD;
    *(float4*)(y + (size_t)row * DD + t * 4) = *(const float4*)(sp + t * 4);
}

extern "C" void kernel_launch(void* const* d_in, const int* in_sizes, int n_in,
                              void* d_out, int out_size, void* d_ws, size_t ws_size,
                              hipStream_t stream)
{
    const float* x_de   = (const float*)d_in[0];
    const float* x_ar   = (const float*)d_in[1];
    const int*   doc    = (const int*)d_in[2];
    /* d_in[3] = begin (unused by reference) */
    const float* Wqkv   = (const float*)d_in[4];
    const float* Wo     = (const float*)d_in[5];
    const float* Wup    = (const float*)d_in[6];
    const float* Wdown  = (const float*)d_in[7];
    const float* attn_nw= (const float*)d_in[8];
    const float* ffn_nw = (const float*)d_in[9];
    const float* de_nw  = (const float*)d_in[10];
    const float* de_W   = (const float*)d_in[11];
    const float* ar_nw  = (const float*)d_in[12];
    const float* ar_W   = (const float*)d_in[13];
    const float* pos_emb= (const float*)d_in[14];
    const float* ar_bias= (const float*)d_in[15];
    float* out = (float*)d_out;

    // workspace layout (floats):
    //   x   : BSROWS*DD                    =  2,621,440
    //   h   : BSROWS*DD                    =  2,621,440
    //   u   : BSROWS*2*FF                  = 14,417,920  (qkv at +0, o at +BSROWS*3*DD)
    //   qkv-heads q|k|v : 3 * BB*HH*SS*AA  =  7,864,320  (reused as g after attention)
    float* ws = (float*)d_ws;
    float* x   = ws;
    float* h   = x + (size_t)BSROWS * DD;
    float* u   = h + (size_t)BSROWS * DD;
    float* qkv = u;
    float* o   = u + (size_t)BSROWS * 3 * DD;
    float* qb  = u + (size_t)BSROWS * 2 * FF;
    float* kb  = qb + (size_t)BB * HH * SS * AA;
    float* vb  = kb + (size_t)BB * HH * SS * AA;
    float* g   = qb;   // q/k/v dead after attention; g needs BSROWS*FF <= 3*BB*HH*SS*AA

    // ---- preprocess: (x_de + pos_emb) -> rmsnorm -> @de_W^T ; same for ar ----
    int deRows = BB * NBLK * KTOK;   // 512
    int arRows = BB * NBLK * NTOK;   // 2048
    addnorm_kernel<<<deRows, 256, 0, stream>>>(x_de, pos_emb, de_nw, h, KTOK);
    addnorm_kernel<<<arRows, 256, 0, stream>>>(x_ar, ar_bias, ar_nw, h + (size_t)deRows * DD, NTOK);
    gemm_nt<<<dim3(DD / 64, deRows / 64), 256, 0, stream>>>(h, de_W, x, deRows, DD, DD, KTOK, 0, 0);
    gemm_nt<<<dim3(DD / 64, arRows / 64), 256, 0, stream>>>(h + (size_t)deRows * DD, ar_W, x, arRows, DD, DD, NTOK, KTOK, 0);

    for (int l = 0; l < LL; ++l) {
        const float* wqkv = Wqkv  + (size_t)l * 3 * DD * DD;
        const float* wo   = Wo    + (size_t)l * DD * DD;
        const float* wup  = Wup   + (size_t)l * 2 * FF * DD;
        const float* wdn  = Wdown + (size_t)l * DD * FF;

        addnorm_kernel<<<BSROWS, 256, 0, stream>>>(x, nullptr, attn_nw + (size_t)l * DD, h, 1);
        gemm_nt<<<dim3(3 * DD / 64, BSROWS / 64), 256, 0, stream>>>(h, wqkv, qkv, BSROWS, 3 * DD, DD, 0, 0, 0);
        qkprep_kernel<<<BB * SS * HH, 64, 0, stream>>>(qkv, qb, kb, vb);
        attn_kernel<<<BB * HH * SS, 64, 0, stream>>>(qb, kb, vb, doc, o);
        gemm_nt<<<dim3(DD / 64, BSROWS / 64), 256, 0, stream>>>(o, wo, x, BSROWS, DD, DD, 0, 0, 1);

        addnorm_kernel<<<BSROWS, 256, 0, stream>>>(x, nullptr, ffn_nw + (size_t)l * DD, h, 1);
        gemm_nt<<<dim3(2 * FF / 64, BSROWS / 64), 256, 0, stream>>>(h, wup, u, BSROWS, 2 * FF, DD, 0, 0, 0);
        gate_kernel<<<(BSROWS * (FF / 4)) / 256, 256, 0, stream>>>(u, g);
        gemm_nt<<<dim3(DD / 64, BSROWS / 64), 256, 0, stream>>>(g, wdn, x, BSROWS, DD, FF, 0, 0, 1);
    }

    copyout_kernel<<<BB * NBLK * NTOK, 256, 0, stream>>>(x, out);
}

// Round 2
// 4213.135 us; speedup vs baseline: 1.8463x; 1.8463x over previous
//
#include <hip/hip_runtime.h>
#include <math.h>

#define BB 2
#define NBLK 16
#define KTOK 16
#define NTOK 64
#define DD 1024
#define HH 16
#define AA 64
#define FF 2816
#define LL 4
#define WINW 4
#define EE 80
#define SS 1280
#define BSROWS (BB*SS)   /* 2560 */
#define EPSF 1e-5f

typedef __bf16 bf16;
typedef __attribute__((ext_vector_type(8))) __bf16 bf16x8;
typedef __attribute__((ext_vector_type(4))) __bf16 bf16x4;
typedef __attribute__((ext_vector_type(4))) float f32x4;

#define AS1C(p) ((const __attribute__((address_space(1))) void*)(p))
#define AS3(p)  ((__attribute__((address_space(3))) void*)(p))

// ---------------------------------------------------------------------------
// f32 -> bf16 conversion (weights), grid-stride, float4 granularity.
// ---------------------------------------------------------------------------
__global__ __launch_bounds__(256) void f2bf_kernel(
    const float* __restrict__ s, bf16* __restrict__ d, int n)
{
    int stride = gridDim.x * 256 * 4;
    for (int i = (blockIdx.x * 256 + threadIdx.x) * 4; i < n; i += stride) {
        float4 v = *(const float4*)(s + i);
        bf16x4 o;
        o.x = (bf16)v.x; o.y = (bf16)v.y; o.z = (bf16)v.z; o.w = (bf16)v.w;
        *(bf16x4*)(d + i) = o;
    }
}

// ---------------------------------------------------------------------------
// Fused (optional bias add) + RMSNorm over D=1024 -> bf16 output.
// One block (256 thr) per row. bias row = row % biasRows; bias may be null.
// ---------------------------------------------------------------------------
__global__ __launch_bounds__(256) void addnorm_kernel(
    const float* __restrict__ src, const float* __restrict__ bias,
    const float* __restrict__ w, bf16* __restrict__ dst, int biasRows)
{
    int row = blockIdx.x;
    int t = threadIdx.x;
    const float* sp = src + (size_t)row * DD;
    float4 v = *(const float4*)(sp + t * 4);
    if (bias) {
        const float* bp = bias + (size_t)(row % biasRows) * DD;
        float4 bv = *(const float4*)(bp + t * 4);
        v.x += bv.x; v.y += bv.y; v.z += bv.z; v.w += bv.w;
    }
    float ss = v.x*v.x + v.y*v.y + v.z*v.z + v.w*v.w;
    __shared__ float red[4];
    #pragma unroll
    for (int off = 32; off; off >>= 1) ss += __shfl_xor(ss, off);
    int wid = t >> 6;
    if ((t & 63) == 0) red[wid] = ss;
    __syncthreads();
    float tot = red[0] + red[1] + red[2] + red[3];
    float rs = rsqrtf(tot * (1.0f / DD) + EPSF);
    float4 wv = *(const float4*)(w + t * 4);
    bf16x4 o;
    o.x = (bf16)(v.x * rs * wv.x); o.y = (bf16)(v.y * rs * wv.y);
    o.z = (bf16)(v.z * rs * wv.z); o.w = (bf16)(v.w * rs * wv.w);
    *(bf16x4*)(dst + (size_t)row * DD + t * 4) = o;
}

// ---------------------------------------------------------------------------
// C[M,N] = A[M,K](bf16) @ W[N,K](bf16)^T -> f32 C (+ optional residual RMW).
// 128x128 tile, BK=32, 256 threads = 4 waves each owning a 64x64 quadrant.
// mfma_f32_16x16x32_bf16; staging via global_load_lds width=16 (linear LDS).
// Optional row remap: r = (m/remapT)*EE + remapOff + (m%remapT).
// Requires M%128==0, N%128==0, K%32==0.
// ---------------------------------------------------------------------------
__global__ __launch_bounds__(256) void gemm_bf16(
    const bf16* __restrict__ A, const bf16* __restrict__ W,
    float* __restrict__ C, int M, int N, int Kd,
    int remapT, int remapOff, int addRes)
{
    __shared__ bf16 As[128 * 32];
    __shared__ bf16 Bs[128 * 32];
    int t = threadIdx.x;
    int wid = t >> 6, lane = t & 63;
    int n0 = blockIdx.x * 128, m0 = blockIdx.y * 128;
    int wr = wid >> 1, wc = wid & 1;

    // staging: each wave fills rows [wid*16, wid*16+16) and [64+wid*16, ...)
    int srow = lane >> 2;            // 0..15
    int scol = (lane & 3) * 8;       // 0,8,16,24
    const bf16* gA0 = A + (size_t)(m0 + wid * 16 + srow) * Kd + scol;
    const bf16* gA1 = gA0 + (size_t)64 * Kd;
    const bf16* gB0 = W + (size_t)(n0 + wid * 16 + srow) * Kd + scol;
    const bf16* gB1 = gB0 + (size_t)64 * Kd;
    bf16* lA0 = As + (wid * 16) * 32;        // wave-uniform LDS bases
    bf16* lA1 = As + (64 + wid * 16) * 32;
    bf16* lB0 = Bs + (wid * 16) * 32;
    bf16* lB1 = Bs + (64 + wid * 16) * 32;

    f32x4 acc[4][4] = {};
    int arow = wr * 64 + (lane & 15);
    int brow = wc * 64 + (lane & 15);
    int koff = (lane >> 4) * 8;

    for (int k0 = 0; k0 < Kd; k0 += 32) {
        __builtin_amdgcn_global_load_lds(AS1C(gA0 + k0), AS3(lA0), 16, 0, 0);
        __builtin_amdgcn_global_load_lds(AS1C(gA1 + k0), AS3(lA1), 16, 0, 0);
        __builtin_amdgcn_global_load_lds(AS1C(gB0 + k0), AS3(lB0), 16, 0, 0);
        __builtin_amdgcn_global_load_lds(AS1C(gB1 + k0), AS3(lB1), 16, 0, 0);
        __syncthreads();
        bf16x8 af[4], bfr[4];
        #pragma unroll
        for (int mt = 0; mt < 4; ++mt)
            af[mt] = *(const bf16x8*)&As[(arow + mt * 16) * 32 + koff];
        #pragma unroll
        for (int nt = 0; nt < 4; ++nt)
            bfr[nt] = *(const bf16x8*)&Bs[(brow + nt * 16) * 32 + koff];
        #pragma unroll
        for (int mt = 0; mt < 4; ++mt)
            #pragma unroll
            for (int nt = 0; nt < 4; ++nt)
                acc[mt][nt] = __builtin_amdgcn_mfma_f32_16x16x32_bf16(
                    af[mt], bfr[nt], acc[mt][nt], 0, 0, 0);
        __syncthreads();
    }

    #pragma unroll
    for (int mt = 0; mt < 4; ++mt) {
        #pragma unroll
        for (int nt = 0; nt < 4; ++nt) {
            int col = n0 + wc * 64 + nt * 16 + (lane & 15);
            int rbase = m0 + wr * 64 + mt * 16 + (lane >> 4) * 4;
            #pragma unroll
            for (int j = 0; j < 4; ++j) {
                int m = rbase + j;
                int r = remapT ? ((m / remapT) * EE + remapOff + (m % remapT)) : m;
                float val = acc[mt][nt][j];
                float* cp = C + (size_t)r * N + col;
                if (addRes) val += *cp;
                *cp = val;
            }
        }
    }
}

// ---------------------------------------------------------------------------
// Per (b,s,h) wave: split qkv, l2norm(q,k), rope(q,k). q,v -> (B,H,S,A);
// k -> transposed (B,H,A,S) for coalesced score dots.
// ---------------------------------------------------------------------------
__global__ __launch_bounds__(64) void qkprep_kernel(
    const float* __restrict__ qkv, float* __restrict__ q,
    float* __restrict__ kt, float* __restrict__ v)
{
    int id = blockIdx.x;
    int h = id % HH;
    int s = (id / HH) % SS;
    int b = id / (HH * SS);
    int lane = threadIdx.x;
    const float* base = qkv + (size_t)(b * SS + s) * (3 * DD) + h * AA;
    float qv = base[lane];
    float kv = base[DD + lane];
    float vv = base[2 * DD + lane];
    float sq = qv * qv, sk = kv * kv;
    #pragma unroll
    for (int off = 32; off; off >>= 1) {
        sq += __shfl_xor(sq, off);
        sk += __shfl_xor(sk, off);
    }
    qv = qv / fmaxf(sqrtf(sq), EPSF);
    kv = kv / fmaxf(sqrtf(sk), EPSF);
    int j = lane & 31;
    bool hi = lane >= 32;
    float invf = __expf(-9.210340371976184f * (float)j * (1.0f / 32.0f));
    float ang = (float)s * invf;
    float c = cosf(ang), sn = sinf(ang);
    float qp = __shfl_xor(qv, 32);
    float kp = __shfl_xor(kv, 32);
    float qo = hi ? (qv * c - qp * sn) : (qv * c + qp * sn);
    float ko = hi ? (kv * c - kp * sn) : (kv * c + kp * sn);
    size_t bh = (size_t)(b * HH + h);
    q[(bh * SS + s) * AA + lane] = qo;
    kt[(bh * AA + lane) * SS + s] = ko;
    v[(bh * SS + s) * AA + lane] = vv;
}

// ---------------------------------------------------------------------------
// One wave per (b,h,query). Keys confined to blocks [bq-3, bq] (<=320 keys).
// Output written bf16 in (B,S,D) layout for the Wo GEMM.
// ---------------------------------------------------------------------------
__global__ __launch_bounds__(64) void attn_kernel(
    const float* __restrict__ q, const float* __restrict__ kt,
    const float* __restrict__ v, const int* __restrict__ doc,
    bf16* __restrict__ o)
{
    __shared__ float sQ[AA];
    __shared__ float sP[4 * EE];
    __shared__ int sDoc[NBLK];
    int id = blockIdx.x;
    int qi = id % SS;
    int h = (id / SS) % HH;
    int b = id / (SS * HH);
    int lane = threadIdx.x;
    if (lane < NBLK) sDoc[lane] = doc[b * NBLK + lane];
    size_t bh = (size_t)(b * HH + h);
    sQ[lane] = q[(bh * SS + qi) * AA + lane];
    __syncthreads();
    int bq = qi / EE, rq = qi - bq * EE;
    bool tokq = rq >= KTOK;
    int docq = sDoc[bq];
    int kstart = (bq >= (WINW - 1) ? bq - (WINW - 1) : 0) * EE;
    int kend = (bq + 1) * EE;
    float mx = -3.0e38f;
    for (int kk = kstart + lane; kk < kend; kk += 64) {
        int bk = kk / EE, rk = kk - bk * EE;
        bool tokk = rk >= KTOK;
        int dock = sDoc[bk];
        int dpk = sDoc[bk > 0 ? bk - 1 : 0];
        bool tt = tokq && tokk && (qi >= kk) && (bq < bk + WINW) && (docq == dock);
        bool lm = ((tokq && docq == dpk) || !tokq) && !tokk && (bq == bk);
        float sc = -3.0e38f;
        if (tt || lm) {
            const float* kp = kt + (bh * AA) * SS + kk;
            float accd = 0.f;
            #pragma unroll
            for (int d = 0; d < AA; ++d) accd += sQ[d] * kp[(size_t)d * SS];
            sc = accd * 0.125f;
        }
        sP[kk - kstart] = sc;
        mx = fmaxf(mx, sc);
    }
    #pragma unroll
    for (int off = 32; off; off >>= 1) mx = fmaxf(mx, __shfl_xor(mx, off));
    float sum = 0.f;
    for (int kk = kstart + lane; kk < kend; kk += 64) {
        float e = __expf(sP[kk - kstart] - mx);
        sP[kk - kstart] = e;
        sum += e;
    }
    #pragma unroll
    for (int off = 32; off; off >>= 1) sum += __shfl_xor(sum, off);
    __syncthreads();
    float invs = 1.0f / sum;
    float accv = 0.f;
    const float* vp = v + (bh * SS) * AA + lane;
    for (int kk = kstart; kk < kend; ++kk)
        accv += sP[kk - kstart] * vp[(size_t)kk * AA];
    o[((size_t)b * SS + qi) * DD + h * AA + lane] = (bf16)(accv * invs);
}

// ---------------------------------------------------------------------------
// g = silu(u1) * u2 -> bf16,  u = [u1 | u2] with row length 2F.
// ---------------------------------------------------------------------------
__global__ __launch_bounds__(256) void gate_kernel(
    const float* __restrict__ u, bf16* __restrict__ g)
{
    int idx = blockIdx.x * 256 + threadIdx.x;   // float4 index
    int m = idx / (FF / 4);
    int f4 = idx % (FF / 4);
    const float* up = u + (size_t)m * (2 * FF) + f4 * 4;
    float4 a = *(const float4*)up;
    float4 b = *(const float4*)(up + FF);
    bf16x4 r;
    r.x = (bf16)(a.x / (1.f + __expf(-a.x)) * b.x);
    r.y = (bf16)(a.y / (1.f + __expf(-a.y)) * b.y);
    r.z = (bf16)(a.z / (1.f + __expf(-a.z)) * b.z);
    r.w = (bf16)(a.w / (1.f + __expf(-a.w)) * b.w);
    *(bf16x4*)(g + (size_t)m * FF + f4 * 4) = r;
}

// ---------------------------------------------------------------------------
// y[b,blk,n,:] = x[b, blk*E + K + n, :]
// ---------------------------------------------------------------------------
__global__ __launch_bounds__(256) void copyout_kernel(
    const float* __restrict__ x, float* __restrict__ y)
{
    int row = blockIdx.x;      // 0 .. 2047
    int t = threadIdx.x;
    int b = row / (NBLK * NTOK);
    int rem = row % (NBLK * NTOK);
    int blk = rem / NTOK;
    int n = rem % NTOK;
    const float* sp = x + ((size_t)b * SS + blk * EE + KTOK + n) * DD;
    *(float4*)(y + (size_t)row * DD + t * 4) = *(const float4*)(sp + t * 4);
}

extern "C" void kernel_launch(void* const* d_in, const int* in_sizes, int n_in,
                              void* d_out, int out_size, void* d_ws, size_t ws_size,
                              hipStream_t stream)
{
    const float* x_de   = (const float*)d_in[0];
    const float* x_ar   = (const float*)d_in[1];
    const int*   doc    = (const int*)d_in[2];
    const float* Wqkv   = (const float*)d_in[4];
    const float* Wo     = (const float*)d_in[5];
    const float* Wup    = (const float*)d_in[6];
    const float* Wdown  = (const float*)d_in[7];
    const float* attn_nw= (const float*)d_in[8];
    const float* ffn_nw = (const float*)d_in[9];
    const float* de_nw  = (const float*)d_in[10];
    const float* de_W   = (const float*)d_in[11];
    const float* ar_nw  = (const float*)d_in[12];
    const float* ar_W   = (const float*)d_in[13];
    const float* pos_emb= (const float*)d_in[14];
    const float* ar_bias= (const float*)d_in[15];
    float* out = (float*)d_out;

    // ---- workspace layout ----
    // f32: x (2,621,440) | u (14,417,920; qkv aliases u[0:7,864,320]) |
    //      qb,kb,vb (3 x 2,621,440)
    // bf16: h_bf (2,621,440) | o_bf (2,621,440) | wbf (12,845,056)
    // g_bf(7,208,960 bf16) aliases qb+kb region (dead after attention).
    float* ws = (float*)d_ws;
    float* x   = ws;
    float* u   = x + (size_t)BSROWS * DD;
    float* qkv = u;
    float* qb  = u + (size_t)BSROWS * 2 * FF;
    float* kb  = qb + (size_t)BB * HH * SS * AA;
    float* vb  = kb + (size_t)BB * HH * SS * AA;
    bf16*  g_bf = (bf16*)qb;
    bf16*  h_bf = (bf16*)(vb + (size_t)BB * HH * SS * AA);
    bf16*  o_bf = h_bf + (size_t)BSROWS * DD;
    bf16*  wbf  = o_bf + (size_t)BSROWS * DD;
    bf16*  wqkv_bf = wbf;
    bf16*  wo_bf   = wqkv_bf + (size_t)3 * DD * DD;
    bf16*  wup_bf  = wo_bf + (size_t)DD * DD;
    bf16*  wdn_bf  = wup_bf + (size_t)2 * FF * DD;

    // ---- preprocess ----
    int deRows = BB * NBLK * KTOK;   // 512
    int arRows = BB * NBLK * NTOK;   // 2048
    f2bf_kernel<<<512, 256, 0, stream>>>(de_W, wqkv_bf, DD * DD);
    f2bf_kernel<<<512, 256, 0, stream>>>(ar_W, wo_bf, DD * DD);
    addnorm_kernel<<<deRows, 256, 0, stream>>>(x_de, pos_emb, de_nw, h_bf, KTOK);
    addnorm_kernel<<<arRows, 256, 0, stream>>>(x_ar, ar_bias, ar_nw, h_bf + (size_t)deRows * DD, NTOK);
    gemm_bf16<<<dim3(DD / 128, deRows / 128), 256, 0, stream>>>(
        h_bf, wqkv_bf, x, deRows, DD, DD, KTOK, 0, 0);
    gemm_bf16<<<dim3(DD / 128, arRows / 128), 256, 0, stream>>>(
        h_bf + (size_t)deRows * DD, wo_bf, x, arRows, DD, DD, NTOK, KTOK, 0);

    for (int l = 0; l < LL; ++l) {
        const float* wqkv = Wqkv  + (size_t)l * 3 * DD * DD;
        const float* wo   = Wo    + (size_t)l * DD * DD;
        const float* wup  = Wup   + (size_t)l * 2 * FF * DD;
        const float* wdn  = Wdown + (size_t)l * DD * FF;

        f2bf_kernel<<<2048, 256, 0, stream>>>(wqkv, wqkv_bf, 3 * DD * DD);
        f2bf_kernel<<<1024, 256, 0, stream>>>(wo, wo_bf, DD * DD);
        f2bf_kernel<<<2048, 256, 0, stream>>>(wup, wup_bf, 2 * FF * DD);
        f2bf_kernel<<<2048, 256, 0, stream>>>(wdn, wdn_bf, DD * FF);

        addnorm_kernel<<<BSROWS, 256, 0, stream>>>(x, nullptr, attn_nw + (size_t)l * DD, h_bf, 1);
        gemm_bf16<<<dim3(3 * DD / 128, BSROWS / 128), 256, 0, stream>>>(
            h_bf, wqkv_bf, qkv, BSROWS, 3 * DD, DD, 0, 0, 0);
        qkprep_kernel<<<BB * SS * HH, 64, 0, stream>>>(qkv, qb, kb, vb);
        attn_kernel<<<BB * HH * SS, 64, 0, stream>>>(qb, kb, vb, doc, o_bf);
        gemm_bf16<<<dim3(DD / 128, BSROWS / 128), 256, 0, stream>>>(
            o_bf, wo_bf, x, BSROWS, DD, DD, 0, 0, 1);

        addnorm_kernel<<<BSROWS, 256, 0, stream>>>(x, nullptr, ffn_nw + (size_t)l * DD, h_bf, 1);
        gemm_bf16<<<dim3(2 * FF / 128, BSROWS / 128), 256, 0, stream>>>(
            h_bf, wup_bf, u, BSROWS, 2 * FF, DD, 0, 0, 0);
        gate_kernel<<<(BSROWS * (FF / 4)) / 256, 256, 0, stream>>>(u, g_bf);
        gemm_bf16<<<dim3(DD / 128, BSROWS / 128), 256, 0, stream>>>(
            g_bf, wdn_bf, x, BSROWS, DD, FF, 0, 0, 1);
    }

    copyout_kernel<<<BB * NBLK * NTOK, 256, 0, stream>>>(x, out);
}